// Round 10
// baseline (236.403 us; speedup 1.0000x reference)
//
#include <hip/hip_runtime.h>

namespace {

constexpr int B  = 8;
constexpr int L  = 4096;
constexpr int D  = 1024;
constexpr int P  = L / 2;        // 2048 pair-rows
constexpr int TJ = 64;           // columns per chunk (256 B slice)
constexpr int TP = 32;           // output pairs per block (64 rows x 256 cols)
constexpr int RP = TP + TJ;      // 96 staged pair-rows per chunk
constexpr int RR = 2 * RP;       // 192 staged raw rows
constexpr int NT = 512;          // 8 waves
constexpr int NW = NT / 64;
constexpr int GC = 4;            // chunks per block -> 1 KB write bursts
constexpr int NXG = D / (GC * TJ);       // 4 column groups per row
constexpr int NCH = RR * TJ * 4 / 1024;  // 48 x 1KiB DMA chunks per stage
constexpr int CPW = NCH / NW;            // 6 per wave
static_assert(CPW == 6, "chunk math");
static_assert(RR * TJ * 4 == 48 * 1024, "LDS = 48 KiB");

typedef float floatx4 __attribute__((ext_vector_type(4)));

// Async 16B global->LDS DMA. LDS dest is wave-uniform base + lane*16 (linear).
__device__ __forceinline__ void async_ld16(const float* g, float* l) {
  __builtin_amdgcn_global_load_lds(
      (const __attribute__((address_space(1))) void*)g,
      (__attribute__((address_space(3))) void*)l, 16, 0, 0);
}

// Block owns output pairs [p0, p0+32) x 256 columns (group x4), batch pinned
// to XCD via bid&7. Walks 4 column chunks with the proven round-3 stage/drain
// math, defers e/o in registers (32 VGPR), then transposes through the dead
// input LDS buffer and stores 1 KB row-major non-temporal bursts: 4x fewer
// DRAM page activations than 256 B slices, and each 4 KB output row is
// completed by 4 consecutive same-XCD blocks.
__global__ __launch_bounds__(NT, 6)
void swd_kernel(const float* __restrict__ v, float* __restrict__ out) {
  const int bid  = blockIdx.x;     // 2048 blocks
  const int b    = bid & 7;        // batch == XCD (round-robin dispatch)
  const int s    = bid >> 3;       // 0..255 within XCD, sequential in time
  const int x4   = s & 3;          // column group (fastest: row completion)
  const int band = s >> 2;         // 0..63, monotone within XCD
  const int p0   = band * TP;

  __shared__ float lds[RR * TJ];   // 48 KiB; raw row r of chunk at [r*TJ ...)

  const int tid  = threadIdx.x;
  const int wave = tid >> 6;
  const int lane = tid & 63;

  // stage lane geometry (per 1 KiB chunk: 4 raw rows x 256 B)
  const int f  = lane & 15;        // 16 B quad within 256 B row slice
  const int rc = lane >> 4;        // raw row within chunk

  // drain geometry: thread owns column quad g (0..15), output pair c (0..31)
  const int g = tid & 15;
  const int c = tid >> 4;
  const int krb = 2 * c - 8 * g + 2 * (TJ - 1) - 6;   // in [0, 182]

  const float* __restrict__ vb   = v   + (size_t)b * L * D;
  float*       __restrict__ outb = out + (size_t)b * L * D;

  float4 eG[GC], oG[GC];

#pragma unroll
  for (int xx = 0; xx < GC; ++xx) {
    const int x  = x4 * GC + xx;
    const int j0 = x * TJ;
    const int r0 = p0 - (j0 + TJ - 2);   // lowest staged pair index (mod P)

    // ---- Stage chunk x: 48 KiB window of raw 256 B row slices
#pragma unroll
    for (int i = 0; i < CPW; ++i) {
      const int C   = wave + NW * i;     // 1 KiB chunk index, wave-uniform
      const int kr  = 4 * C + rc;        // raw staged row 0..191
      const int q   = (r0 + (kr >> 1)) & (P - 1);
      const int row = 2 * q + (kr & 1);
      async_ld16(vb + (size_t)row * D + j0 + 4 * f, &lds[C * 256]);
    }
    asm volatile("s_waitcnt vmcnt(0)" ::: "memory");
    __syncthreads();

    // ---- Drain: pair min/max fold + shear select (proven math)
    float4 m[4], M[4];
#pragma unroll
    for (int u = 0; u < 4; ++u) {
      const float4 a0 = *(const float4*)&lds[(krb + 2 * u)     * TJ + 4 * g];
      const float4 a1 = *(const float4*)&lds[(krb + 2 * u + 1) * TJ + 4 * g];
      m[u].x = fminf(a0.x, a1.x); M[u].x = fmaxf(a0.x, a1.x);
      m[u].y = fminf(a0.y, a1.y); M[u].y = fmaxf(a0.y, a1.y);
      m[u].z = fminf(a0.z, a1.z); M[u].z = fmaxf(a0.z, a1.z);
      m[u].w = fminf(a0.w, a1.w); M[u].w = fmaxf(a0.w, a1.w);
    }
    const bool sp = (j0 == 0) && (g == 0);  // column 0: h_0 = 0, not -1
    float4 e, o;
    e.x = sp ? m[2].x : m[3].x; e.y = m[2].y; e.z = m[1].z; e.w = m[0].w;
    o.x = sp ? M[2].x : M[3].x; o.y = M[2].y; o.z = M[1].z; o.w = M[0].w;
    eG[xx] = e; oG[xx] = o;
    __syncthreads();   // all LDS reads retired before next stage overwrites
  }

  // ---- Transpose + store: two half-passes of 32 rows x 1 KiB (32 KiB
  // staging fits in the now-dead input buffer).
#pragma unroll
  for (int h = 0; h < 2; ++h) {
    if ((c >> 4) == h) {               // c in [16h, 16h+16) owns these rows
      const int r = 2 * c - 32 * h;    // local even row 0..30
#pragma unroll
      for (int xx = 0; xx < GC; ++xx) {
        *(float4*)&lds[(r    ) * 256 + 64 * xx + 4 * g] = eG[xx];
        *(float4*)&lds[(r + 1) * 256 + 64 * xx + 4 * g] = oG[xx];
      }
    }
    __syncthreads();
    // wave w stores rows 4w..4w+3; one instr = one full 1 KiB row-burst
#pragma unroll
    for (int k = 0; k < 4; ++k) {
      const int rl = 4 * wave + k;     // local row 0..31
      const floatx4 val = *(const floatx4*)&lds[rl * 256 + 4 * lane];
      __builtin_nontemporal_store(val,
          (floatx4*)(outb + (size_t)(2 * p0 + 32 * h + rl) * D
                     + 256 * x4 + 4 * lane));
    }
    __syncthreads();   // LDS reads done before h=1 rewrite
  }
}

} // namespace

extern "C" void kernel_launch(void* const* d_in, const int* /*in_sizes*/, int /*n_in*/,
                              void* d_out, int /*out_size*/, void* /*d_ws*/, size_t /*ws_size*/,
                              hipStream_t stream) {
  const float* v = (const float*)d_in[0];
  float* out = (float*)d_out;
  dim3 grid(B * (P / TP) * NXG);   // 2048 blocks: batch = bid&7, then x4, band
  swd_kernel<<<grid, NT, 0, stream>>>(v, out);
}